// Round 17
// baseline (371.408 us; speedup 1.0000x reference)
//
#include <hip/hip_runtime.h>
#include <stdint.h>

typedef short           bf16x8 __attribute__((ext_vector_type(8)));
typedef float           f32x4  __attribute__((ext_vector_type(4)));
typedef float           f32x16 __attribute__((ext_vector_type(16)));
typedef unsigned short  u16;
typedef u16             u16x8  __attribute__((ext_vector_type(8)));
typedef uint32_t        u32;
typedef unsigned long long u64;

#define NB    8
#define NSEQ  2121
#define NPAD  2176      /* 34*64 */
#define MROWS 16968     /* 8*2121 */
#define MPAD  17024     /* 133*128 */
#define NH    12

#if __has_builtin(__builtin_amdgcn_exp2f)
#define EXP2F(x) __builtin_amdgcn_exp2f(x)
#else
#define EXP2F(x) exp2f(x)
#endif

#define INVALID_S   (-90000.0f)

__device__ __forceinline__ u16 f2bf(float f) {
  uint32_t u = __float_as_uint(f);
  u += 0x7fffu + ((u >> 16) & 1u);
  return (u16)(u >> 16);
}

// async 16B global -> LDS (direct, no VGPR roundtrip).
__device__ __forceinline__ void gld_lds16(const void* g, void* l) {
  __builtin_amdgcn_global_load_lds(
      (const __attribute__((address_space(1))) unsigned int*)g,
      (__attribute__((address_space(3))) unsigned int*)l, 16, 0, 0);
}

// ---------------------------------------------------------------- transpose+cast
__global__ void transpose_cast(const float* __restrict__ in, u16* __restrict__ out,
                               int R, int C, int scale_cols, float scale)
{
  __shared__ float tile[32][33];
  const int c0 = blockIdx.x * 32, r0 = blockIdx.y * 32;
  const int tx = threadIdx.x, ty = threadIdx.y;
#pragma unroll
  for (int i = 0; i < 4; i++) {
    const int r = r0 + ty + i * 8;
    tile[ty + i * 8][tx] = in[(size_t)r * C + c0 + tx];
  }
  __syncthreads();
#pragma unroll
  for (int i = 0; i < 4; i++) {
    const int c = c0 + ty + i * 8;
    float v = tile[tx][ty + i * 8];
    if (c < scale_cols) v *= scale;
    out[(size_t)c * R + r0 + tx] = f2bf(v);
  }
}

// ---------------------------------------------------------------- src fp32 -> bf16
__global__ __launch_bounds__(256) void cast_src_bf16(const float* __restrict__ in,
                                                     u16* __restrict__ out)
{
  const size_t i = ((size_t)blockIdx.x * 256 + threadIdx.x) * 8;
  float4 a = *(const float4*)(in + i);
  float4 b = *(const float4*)(in + i + 4);
  u16x8 t;
  t[0] = f2bf(a.x); t[1] = f2bf(a.y); t[2] = f2bf(a.z); t[3] = f2bf(a.w);
  t[4] = f2bf(b.x); t[5] = f2bf(b.y); t[6] = f2bf(b.z); t[7] = f2bf(b.w);
  *(u16x8*)(out + i) = t;
}

// ---------------------------------------------------------------- GEMM1: qkv (dbuf gload_lds)
__global__ __launch_bounds__(256) void gemm_qkv_kernel(
    const u16* __restrict__ srcb, const u16* __restrict__ wt,
    u16* __restrict__ qk, u16* __restrict__ vt)
{
  __shared__ u16 Asf[2][128 * 32];
  __shared__ u16 Bsf[2][128 * 32];
  const int tid  = threadIdx.x;
  const int lane = tid & 63, wave = tid >> 6;
  const int wr = wave >> 1, wc = wave & 1;
  const int col = lane & 15, grp = lane >> 4;
  const int m0 = blockIdx.y * 128, n0 = blockIdx.x * 128;

  const f32x4 fz = {0.f, 0.f, 0.f, 0.f};
  f32x4 acc[4][4];
#pragma unroll
  for (int i = 0; i < 4; i++)
#pragma unroll
    for (int j = 0; j < 4; j++) acc[i][j] = fz;

  const int arow = tid >> 2, akoff = (tid & 3) * 8;
  const u16* ag = srcb + (size_t)(m0 + arow) * 768 + akoff;
  const u16* bg = wt   + (size_t)(n0 + arow) * 768 + akoff;
  const int lofs = wave * 512;

  gld_lds16(ag,                    &Asf[0][lofs]);
  gld_lds16(ag + (size_t)64 * 768, &Asf[0][lofs + 2048]);
  gld_lds16(bg,                    &Bsf[0][lofs]);
  gld_lds16(bg + (size_t)64 * 768, &Bsf[0][lofs + 2048]);

  int cur = 0;
  for (int kb = 0; kb < 768; kb += 32) {
    __syncthreads();
    if (kb + 32 < 768) {
      gld_lds16(ag + kb + 32,                    &Asf[cur ^ 1][lofs]);
      gld_lds16(ag + kb + 32 + (size_t)64 * 768, &Asf[cur ^ 1][lofs + 2048]);
      gld_lds16(bg + kb + 32,                    &Bsf[cur ^ 1][lofs]);
      gld_lds16(bg + kb + 32 + (size_t)64 * 768, &Bsf[cur ^ 1][lofs + 2048]);
    }

    bf16x8 af[4], bfr[4];
#pragma unroll
    for (int mt = 0; mt < 4; mt++) af[mt]  = *(const bf16x8*)&Asf[cur][(wr * 64 + mt * 16 + col) * 32 + grp * 8];
#pragma unroll
    for (int nt = 0; nt < 4; nt++) bfr[nt] = *(const bf16x8*)&Bsf[cur][(wc * 64 + nt * 16 + col) * 32 + grp * 8];
#pragma unroll
    for (int mt = 0; mt < 4; mt++)
#pragma unroll
      for (int nt = 0; nt < 4; nt++)
        acc[mt][nt] = __builtin_amdgcn_mfma_f32_16x16x32_bf16(af[mt], bfr[nt], acc[mt][nt], 0, 0, 0);
    cur ^= 1;
  }

#pragma unroll
  for (int mt = 0; mt < 4; mt++) {
#pragma unroll
    for (int r = 0; r < 4; r++) {
      const int mm = m0 + wr * 64 + mt * 16 + grp * 4 + r;
      if (mm >= MROWS) continue;
      const uint32_t bb = (uint32_t)mm / 2121u;
      const uint32_t nn = (uint32_t)mm - bb * 2121u;
#pragma unroll
      for (int nt = 0; nt < 4; nt++) {
        const int c = n0 + wc * 64 + nt * 16 + col;
        const u16 bits = f2bf(acc[mt][nt][r]);
        if (c < 1536) {
          qk[(size_t)mm * 1536 + c] = bits;
        } else {
          const int hd = c - 1536;
          const int h = hd >> 6, d = hd & 63;
          vt[((size_t)(bb * NH + h) * 64 + d) * NPAD + nn] = bits;
        }
      }
    }
  }
}

// ---------------------------------------------------------------- GEMM2: proj + bias (dbuf gload_lds)
__global__ __launch_bounds__(256) void gemm_proj_kernel(
    const u16* __restrict__ A, const u16* __restrict__ Bt,
    const float* __restrict__ bias, float* __restrict__ out)
{
  __shared__ u16 Asf[2][128 * 32];
  __shared__ u16 Bsf[2][128 * 32];
  const int tid  = threadIdx.x;
  const int lane = tid & 63, wave = tid >> 6;
  const int wr = wave >> 1, wc = wave & 1;
  const int col = lane & 15, grp = lane >> 4;
  const int m0 = blockIdx.y * 128, n0 = blockIdx.x * 128;

  const f32x4 fz = {0.f, 0.f, 0.f, 0.f};
  f32x4 acc[4][4];
#pragma unroll
  for (int i = 0; i < 4; i++)
#pragma unroll
    for (int j = 0; j < 4; j++) acc[i][j] = fz;

  const int arow = tid >> 2, akoff = (tid & 3) * 8;
  const u16* ag = A  + (size_t)(m0 + arow) * 768 + akoff;
  const u16* bg = Bt + (size_t)(n0 + arow) * 768 + akoff;
  const int lofs = wave * 512;

  gld_lds16(ag,                    &Asf[0][lofs]);
  gld_lds16(ag + (size_t)64 * 768, &Asf[0][lofs + 2048]);
  gld_lds16(bg,                    &Bsf[0][lofs]);
  gld_lds16(bg + (size_t)64 * 768, &Bsf[0][lofs + 2048]);

  int cur = 0;
  for (int kb = 0; kb < 768; kb += 32) {
    __syncthreads();
    if (kb + 32 < 768) {
      gld_lds16(ag + kb + 32,                    &Asf[cur ^ 1][lofs]);
      gld_lds16(ag + kb + 32 + (size_t)64 * 768, &Asf[cur ^ 1][lofs + 2048]);
      gld_lds16(bg + kb + 32,                    &Bsf[cur ^ 1][lofs]);
      gld_lds16(bg + kb + 32 + (size_t)64 * 768, &Bsf[cur ^ 1][lofs + 2048]);
    }

    bf16x8 af[4], bfr[4];
#pragma unroll
    for (int mt = 0; mt < 4; mt++) af[mt]  = *(const bf16x8*)&Asf[cur][(wr * 64 + mt * 16 + col) * 32 + grp * 8];
#pragma unroll
    for (int nt = 0; nt < 4; nt++) bfr[nt] = *(const bf16x8*)&Bsf[cur][(wc * 64 + nt * 16 + col) * 32 + grp * 8];
#pragma unroll
    for (int mt = 0; mt < 4; mt++)
#pragma unroll
      for (int nt = 0; nt < 4; nt++)
        acc[mt][nt] = __builtin_amdgcn_mfma_f32_16x16x32_bf16(af[mt], bfr[nt], acc[mt][nt], 0, 0, 0);
    cur ^= 1;
  }

#pragma unroll
  for (int mt = 0; mt < 4; mt++) {
#pragma unroll
    for (int r = 0; r < 4; r++) {
      const int mm = m0 + wr * 64 + mt * 16 + grp * 4 + r;
      if (mm >= MROWS) continue;
#pragma unroll
      for (int nt = 0; nt < 4; nt++) {
        const int c = n0 + wc * 64 + nt * 16 + col;
        out[(size_t)mm * 768 + c] = acc[mt][nt][r] + bias[c];
      }
    }
  }
}

// ---------------------------------------------------------------- attention v6 (best known, passing)
// 8-wave/512-thread blocks, 256 q-rows per block; mask as u64 bitmask;
// static-max softmax; single-barrier dbuf LDS staging.
__global__ __launch_bounds__(512) void attn_kernel(
    const u16* __restrict__ qkbuf, const u16* __restrict__ vt,
    const unsigned char* __restrict__ visu, const unsigned char* __restrict__ text,
    u16* __restrict__ attnout)
{
  __shared__ __align__(16) u16 Ks[2][64][72];
  __shared__ __align__(16) u16 Vs[2][64][72];
  __shared__ __align__(16) u64 mb64[34];
  __shared__ __align__(16) float lduf[8][32];

  const int tid  = threadIdx.x;
  const int lane = tid & 63, wave = tid >> 6;
  const int l31 = lane & 31, h = lane >> 5;

  // XCD swizzle: 864 blocks = 8 * 108; all tiles of one (b,h) on one XCD
  const int fid = blockIdx.x;
  const int swz = (fid & 7) * 108 + (fid >> 3);
  const int qtile = swz % 9;
  const int bh = swz / 9;
  const int b = bh / NH, hh = bh % NH;
  const int qt0 = qtile * 256;
  const int q0 = qt0 + wave * 32;
  const int qrow = q0 + l31;

  // ---- mask bitmask: one u64 per 64-key tile (keys >= 2121 masked) ----
  for (int c = wave; c < 34; c += 8) {
    const int key = c * 64 + lane;
    int mb = 1;
    if (key < 2101)      mb = visu[b * 2101 + key] ? 1 : 0;
    else if (key < 2121) mb = text[b * 20 + (key - 2101)] ? 1 : 0;
    const u64 bal = __ballot(mb != 0);
    if (lane == 0) mb64[c] = bal;
  }

  // Q B-fragments (pre-scaled by log2e/8 via wt scaling); clamp tail rows
  const int qload = (qrow < NSEQ) ? qrow : (NSEQ - 1);
  bf16x8 qf[4];
  {
    const u16* qp = qkbuf + (size_t)(b * NSEQ + qload) * 1536 + hh * 64 + h * 8;
#pragma unroll
    for (int s = 0; s < 4; s++) qf[s] = *(const bf16x8*)(qp + s * 16);
  }

  // per-lane key range (q = qrow)
  int ks, ke, ex;
  if (qrow == 0)        { ks = 0; ke = 2121; ex = 0; }
  else if (qrow < 1601) { ks = 1; ke = 1601; ex = 1; }
  else if (qrow < 2001) { ks = 1; ke = 2001; ex = 1; }
  else if (qrow < 2101) { ks = 1; ke = 2121; ex = 0; }
  else if (qrow < 2121) { ks = 0; ke = 2121; ex = 0; }
  else                  { ks = 0; ke = 0;    ex = 0; }

  // per-tile kv extent + optional text-tail block
  const int hi = (qt0 + 255 < 2120) ? (qt0 + 255) : 2120;
  int ke_tile, extra;
  if (qt0 == 0 || hi >= 2001) { ke_tile = 2121; extra = 0; }
  else if (hi >= 1601)        { ke_tile = 2001; extra = 1; }
  else                        { ke_tile = 1601; extra = 1; }
  const int nkv = (ke_tile + 63) >> 6;
  const int ntot = nkv + extra;

  f32x16 O0, O1;
#pragma unroll
  for (int i = 0; i < 16; i++) { O0[i] = 0.f; O1[i] = 0.f; }
  float lrun = 0.f;

  // staging: 512 threads, one u16x8 of K and one of V each
  const int srow = tid >> 3, skoff = (tid & 7) * 8;
  const size_t vbase = (size_t)(b * NH + hh) * 64 * NPAD;
  const u16* kbase = qkbuf + (size_t)(b * NSEQ + srow) * 1536 + 768 + hh * 64 + skoff;
  const u16* vrow  = vt + vbase + (size_t)srow * NPAD + skoff;

  // prologue: stage tile 0 into buf 0
  *(u16x8*)&Ks[0][srow][skoff] = *(const u16x8*)kbase;
  *(u16x8*)&Vs[0][srow][skoff] = *(const u16x8*)vrow;
  __syncthreads();

  u16x8 kpre, vpre;

  for (int it = 0; it < ntot; ++it) {
    const int cur = it & 1;
    const int kv0 = (it < nkv) ? it * 64 : 2096;  // 2096: 16B-aligned, covers [2101,2121)
    const bool more = (it + 1 < ntot);

    // (1) issue next tile's global loads
    if (more) {
      const int kvn = (it + 1 < nkv) ? (it + 1) * 64 : 2096;
      kpre = *(const u16x8*)(kbase + (size_t)kvn * 1536);
      vpre = *(const u16x8*)(vrow + kvn);
    }

    // (2) compute from buf[cur]
    const int skipl = (kv0 >= ke) && !((ex != 0) && (kv0 < 2121) && (kv0 + 64 > 2101));
    if (!__all(skipl)) {
      f32x16 S0, S1;
#pragma unroll
      for (int i = 0; i < 16; i++) { S0[i] = 0.f; S1[i] = 0.f; }
      __builtin_amdgcn_s_setprio(1);
#pragma unroll
      for (int s = 0; s < 4; s++) {
        const bf16x8 k0 = *(const bf16x8*)&Ks[cur][l31][s * 16 + h * 8];
        const bf16x8 k1 = *(const bf16x8*)&Ks[cur][32 + l31][s * 16 + h * 8];
        S0 = __builtin_amdgcn_mfma_f32_32x32x16_bf16(k0, qf[s], S0, 0, 0, 0);
        S1 = __builtin_amdgcn_mfma_f32_32x32x16_bf16(k1, qf[s], S1, 0, 0, 0);
      }
      __builtin_amdgcn_s_setprio(0);

      // masking: range + mask bit -> INVALID_S (exp2 -> exactly 0)
      const int fastl = (kv0 >= ks) && (kv0 + 64 <= ke);
      const u64 mword = (it < nkv) ? mb64[it] : ((mb64[32] >> 48) | (mb64[33] << 16));
      const bool plain = __all(fastl) && (mword == 0ull);
      if (!plain) {
        const u32 wlo = (u32)mword, whi = (u32)(mword >> 32);
#pragma unroll
        for (int m = 0; m < 4; m++) {
#pragma unroll
          for (int r = 0; r < 4; r++) {
            const int bitpos = 8 * m + 4 * h + r;
            {
              const int key = kv0 + bitpos;
              bool valid = ((key >= ks) && (key < ke)) || ((ex != 0) && (key >= 2101));
              valid = valid && (((wlo >> bitpos) & 1u) == 0u);
              S0[4 * m + r] = valid ? S0[4 * m + r] : INVALID_S;
            }
            {
              const int key = kv0 + 32 + bitpos;
              bool valid = ((key >= ks) && (key < ke)) || ((ex != 0) && (key >= 2101));
              valid = valid && (((whi >> bitpos) & 1u) == 0u);
              S1[4 * m + r] = valid ? S1[4 * m + r] : INVALID_S;
            }
          }
        }
      }

      // static-max softmax: P = exp2(S)
      float ls = 0.f;
#pragma unroll
      for (int i = 0; i < 16; i++) { const float p = EXP2F(S0[i]); S0[i] = p; ls += p; }
#pragma unroll
      for (int i = 0; i < 16; i++) { const float p = EXP2F(S1[i]); S1[i] = p; ls += p; }
      lrun += ls;

      // P -> PV A-fragments (cvt_pk + permlane32_swap)
      bf16x8 pa[4];
      {
        u32 w[8];
#pragma unroll
        for (int j = 0; j < 8; j++) {
          u32 t;
          asm("v_cvt_pk_bf16_f32 %0, %1, %2" : "=v"(t) : "v"(S0[2 * j]), "v"(S0[2 * j + 1]));
          w[j] = t;
        }
        asm("v_permlane32_swap_b32 %0, %1" : "+v"(w[0]), "+v"(w[2]));
        asm("v_permlane32_swap_b32 %0, %1" : "+v"(w[1]), "+v"(w[3]));
        asm("v_permlane32_swap_b32 %0, %1" : "+v"(w[4]), "+v"(w[6]));
        asm("v_permlane32_swap_b32 %0, %1" : "+v"(w[5]), "+v"(w[7]));
        union { u32 u[4]; bf16x8 v; } f0, f1;
        f0.u[0] = w[0]; f0.u[1] = w[1]; f0.u[2] = w[2]; f0.u[3] = w[3];
        f1.u[0] = w[4]; f1.u[1] = w[5]; f1.u[2] = w[6]; f1.u[3] = w[7];
        pa[0] = f0.v; pa[1] = f1.v;
      }
      {
        u32 w[8];
#pragma unroll
        for (int j = 0; j < 8; j++) {
          u32 t;
          asm("v_cvt_pk_bf16_f32 %0, %1, %2" : "=v"(t) : "v"(S1[2 * j]), "v"(S1[2 * j + 1]));
          w[j] = t;
        }
        asm("v_permlane32_swap_b32 %0, %1" : "+v"(w[0]), "+v"(w[2]));
        asm("v_permlane32_swap_b32 %0, %1" : "+v"(w[1]), "+v"(w[3]));
        asm("v_permlane32_swap_b32 %0, %1" : "+v"(w[4]), "+v"(w[6]));
        asm("v_permlane32_swap_b32 %0, %1" : "+v"(w[5]), "+v"(w[7]));
        union { u32 u[4]; bf16x8 v; } f0, f1;
        f0.u[0] = w[0]; f0.u[1] = w[1]; f0.u[2] = w[2]; f0.u[3] = w[3];
        f1.u[0] = w[4]; f1.u[1] = w[5]; f1.u[2] = w[6]; f1.u[3] = w[7];
        pa[2] = f0.v; pa[3] = f1.v;
      }

      // PV: O[q][d] += P[q][k] * Vt[d][k]
      __builtin_amdgcn_s_setprio(1);
#pragma unroll
      for (int ck = 0; ck < 4; ck++) {
        const bf16x8 vf0 = *(const bf16x8*)&Vs[cur][l31][ck * 16 + h * 8];
        const bf16x8 vf1 = *(const bf16x8*)&Vs[cur][32 + l31][ck * 16 + h * 8];
        O0 = __builtin_amdgcn_mfma_f32_32x32x16_bf16(pa[ck], vf0, O0, 0, 0, 0);
        O1 = __builtin_amdgcn_mfma_f32_32x32x16_bf16(pa[ck], vf1, O1, 0, 0, 0);
      }
      __builtin_amdgcn_s_setprio(0);
    }

    // (3) stage next tile into buf[cur^1]
    if (more) {
      *(u16x8*)&Ks[cur ^ 1][srow][skoff] = kpre;
      *(u16x8*)&Vs[cur ^ 1][srow][skoff] = vpre;
    }
    __syncthreads();
  }

  // epilogue: combine lane halves of l, normalize + store
  float ltot = lrun + __shfl_xor(lrun, 32);
  if (h == 0) lduf[wave][l31] = ltot;
#pragma unroll
  for (int m = 0; m < 4; m++) {
    const f32x4 lv = *(const f32x4*)&lduf[wave][8 * m + 4 * h];
#pragma unroll
    for (int r = 0; r < 4; r++) {
      const float linv = (lv[r] > 0.f) ? 1.0f / lv[r] : 0.f;
      const int n = q0 + 8 * m + 4 * h + r;
      if (n >= NSEQ) continue;
      u16* op = attnout + (size_t)(b * NSEQ + n) * 768 + hh * 64 + l31;
      op[0]  = f2bf(O0[4 * m + r] * linv);
      op[32] = f2bf(O1[4 * m + r] * linv);
    }
  }
}

// ----------------------------------------------------------------
extern "C" void kernel_launch(void* const* d_in, const int* in_sizes, int n_in,
                              void* d_out, int out_size, void* d_ws, size_t ws_size,
                              hipStream_t stream) {
  const float* src  = (const float*)d_in[0];
  const unsigned char* visu = (const unsigned char*)d_in[1];
  const unsigned char* text = (const unsigned char*)d_in[2];
  const float* w_qkv = (const float*)d_in[3];
  const float* w_proj = (const float*)d_in[4];
  const float* b_proj = (const float*)d_in[5];
  float* out = (float*)d_out;

  char* ws = (char*)d_ws;
  size_t off = 0;
  auto alloc = [&](size_t bytes) { char* p = ws + off; off += (bytes + 255) & ~(size_t)255; return p; };
  u16* wqkv_t  = (u16*)alloc((size_t)2304 * 768 * 2);
  u16* wproj_t = (u16*)alloc((size_t)768 * 768 * 2);
  u16* qk      = (u16*)alloc((size_t)MPAD * 1536 * 2);
  u16* vtb     = (u16*)alloc((size_t)NB * NH * 64 * NPAD * 2);
  u16* tmp0    = (u16*)alloc((size_t)MPAD * 768 * 2);   // srcb (pre-attn) then attnb
  (void)ws_size; (void)in_sizes; (void)n_in; (void)out_size;

  // Q pre-scale: (1/8) * log2(e)  -> softmax computed in base 2
  transpose_cast<<<dim3(2304 / 32, 768 / 32), dim3(32, 8), 0, stream>>>(w_qkv, wqkv_t, 768, 2304, 768, 0.125f * 1.4426950408889634f);
  transpose_cast<<<dim3(768 / 32, 768 / 32), dim3(32, 8), 0, stream>>>(w_proj, wproj_t, 768, 768, 0, 1.0f);
  cast_src_bf16<<<dim3(6363), dim3(256), 0, stream>>>(src, tmp0);   // 6363*256*8 == MROWS*768
  gemm_qkv_kernel<<<dim3(18, 133), dim3(256), 0, stream>>>(tmp0, wqkv_t, qk, vtb);
  attn_kernel<<<dim3(864), dim3(512), 0, stream>>>(qk, vtb, visu, text, tmp0);
  gemm_proj_kernel<<<dim3(6, 133), dim3(256), 0, stream>>>(tmp0, wproj_t, b_proj, out);
}

// Round 18
// 362.169 us; speedup vs baseline: 1.0255x; 1.0255x over previous
//
#include <hip/hip_runtime.h>
#include <stdint.h>

typedef short           bf16x8 __attribute__((ext_vector_type(8)));
typedef float           f32x4  __attribute__((ext_vector_type(4)));
typedef float           f32x16 __attribute__((ext_vector_type(16)));
typedef unsigned short  u16;
typedef u16             u16x8  __attribute__((ext_vector_type(8)));
typedef uint32_t        u32;
typedef unsigned long long u64;

#define NB    8
#define NSEQ  2121
#define NPAD  2176      /* 34*64 */
#define MROWS 16968     /* 8*2121 */
#define MPAD  17024     /* 133*128 */
#define NH    12

#if __has_builtin(__builtin_amdgcn_exp2f)
#define EXP2F(x) __builtin_amdgcn_exp2f(x)
#else
#define EXP2F(x) exp2f(x)
#endif

#define INVALID_S   (-90000.0f)

__device__ __forceinline__ u16 f2bf(float f) {
  uint32_t u = __float_as_uint(f);
  u += 0x7fffu + ((u >> 16) & 1u);
  return (u16)(u >> 16);
}

// async 16B global -> LDS (direct, no VGPR roundtrip).
__device__ __forceinline__ void gld_lds16(const void* g, void* l) {
  __builtin_amdgcn_global_load_lds(
      (const __attribute__((address_space(1))) unsigned int*)g,
      (__attribute__((address_space(3))) unsigned int*)l, 16, 0, 0);
}

// ---------------------------------------------------------------- transpose+cast
__global__ void transpose_cast(const float* __restrict__ in, u16* __restrict__ out,
                               int R, int C, int scale_cols, float scale)
{
  __shared__ float tile[32][33];
  const int c0 = blockIdx.x * 32, r0 = blockIdx.y * 32;
  const int tx = threadIdx.x, ty = threadIdx.y;
#pragma unroll
  for (int i = 0; i < 4; i++) {
    const int r = r0 + ty + i * 8;
    tile[ty + i * 8][tx] = in[(size_t)r * C + c0 + tx];
  }
  __syncthreads();
#pragma unroll
  for (int i = 0; i < 4; i++) {
    const int c = c0 + ty + i * 8;
    float v = tile[tx][ty + i * 8];
    if (c < scale_cols) v *= scale;
    out[(size_t)c * R + r0 + tx] = f2bf(v);
  }
}

// ---------------------------------------------------------------- src fp32 -> bf16
__global__ __launch_bounds__(256) void cast_src_bf16(const float* __restrict__ in,
                                                     u16* __restrict__ out)
{
  const size_t i = ((size_t)blockIdx.x * 256 + threadIdx.x) * 8;
  float4 a = *(const float4*)(in + i);
  float4 b = *(const float4*)(in + i + 4);
  u16x8 t;
  t[0] = f2bf(a.x); t[1] = f2bf(a.y); t[2] = f2bf(a.z); t[3] = f2bf(a.w);
  t[4] = f2bf(b.x); t[5] = f2bf(b.y); t[6] = f2bf(b.z); t[7] = f2bf(b.w);
  *(u16x8*)(out + i) = t;
}

// ---------------------------------------------------------------- GEMM1: qkv (dbuf gload_lds)
__global__ __launch_bounds__(256) void gemm_qkv_kernel(
    const u16* __restrict__ srcb, const u16* __restrict__ wt,
    u16* __restrict__ qk, u16* __restrict__ vt)
{
  __shared__ u16 Asf[2][128 * 32];
  __shared__ u16 Bsf[2][128 * 32];
  const int tid  = threadIdx.x;
  const int lane = tid & 63, wave = tid >> 6;
  const int wr = wave >> 1, wc = wave & 1;
  const int col = lane & 15, grp = lane >> 4;
  const int m0 = blockIdx.y * 128, n0 = blockIdx.x * 128;

  const f32x4 fz = {0.f, 0.f, 0.f, 0.f};
  f32x4 acc[4][4];
#pragma unroll
  for (int i = 0; i < 4; i++)
#pragma unroll
    for (int j = 0; j < 4; j++) acc[i][j] = fz;

  const int arow = tid >> 2, akoff = (tid & 3) * 8;
  const u16* ag = srcb + (size_t)(m0 + arow) * 768 + akoff;
  const u16* bg = wt   + (size_t)(n0 + arow) * 768 + akoff;
  const int lofs = wave * 512;

  gld_lds16(ag,                    &Asf[0][lofs]);
  gld_lds16(ag + (size_t)64 * 768, &Asf[0][lofs + 2048]);
  gld_lds16(bg,                    &Bsf[0][lofs]);
  gld_lds16(bg + (size_t)64 * 768, &Bsf[0][lofs + 2048]);

  int cur = 0;
  for (int kb = 0; kb < 768; kb += 32) {
    __syncthreads();
    if (kb + 32 < 768) {
      gld_lds16(ag + kb + 32,                    &Asf[cur ^ 1][lofs]);
      gld_lds16(ag + kb + 32 + (size_t)64 * 768, &Asf[cur ^ 1][lofs + 2048]);
      gld_lds16(bg + kb + 32,                    &Bsf[cur ^ 1][lofs]);
      gld_lds16(bg + kb + 32 + (size_t)64 * 768, &Bsf[cur ^ 1][lofs + 2048]);
    }

    bf16x8 af[4], bfr[4];
#pragma unroll
    for (int mt = 0; mt < 4; mt++) af[mt]  = *(const bf16x8*)&Asf[cur][(wr * 64 + mt * 16 + col) * 32 + grp * 8];
#pragma unroll
    for (int nt = 0; nt < 4; nt++) bfr[nt] = *(const bf16x8*)&Bsf[cur][(wc * 64 + nt * 16 + col) * 32 + grp * 8];
#pragma unroll
    for (int mt = 0; mt < 4; mt++)
#pragma unroll
      for (int nt = 0; nt < 4; nt++)
        acc[mt][nt] = __builtin_amdgcn_mfma_f32_16x16x32_bf16(af[mt], bfr[nt], acc[mt][nt], 0, 0, 0);
    cur ^= 1;
  }

#pragma unroll
  for (int mt = 0; mt < 4; mt++) {
#pragma unroll
    for (int r = 0; r < 4; r++) {
      const int mm = m0 + wr * 64 + mt * 16 + grp * 4 + r;
      if (mm >= MROWS) continue;
      const uint32_t bb = (uint32_t)mm / 2121u;
      const uint32_t nn = (uint32_t)mm - bb * 2121u;
#pragma unroll
      for (int nt = 0; nt < 4; nt++) {
        const int c = n0 + wc * 64 + nt * 16 + col;
        const u16 bits = f2bf(acc[mt][nt][r]);
        if (c < 1536) {
          qk[(size_t)mm * 1536 + c] = bits;
        } else {
          const int hd = c - 1536;
          const int h = hd >> 6, d = hd & 63;
          vt[((size_t)(bb * NH + h) * 64 + d) * NPAD + nn] = bits;
        }
      }
    }
  }
}

// ---------------------------------------------------------------- GEMM2: proj + bias (dbuf gload_lds)
__global__ __launch_bounds__(256) void gemm_proj_kernel(
    const u16* __restrict__ A, const u16* __restrict__ Bt,
    const float* __restrict__ bias, float* __restrict__ out)
{
  __shared__ u16 Asf[2][128 * 32];
  __shared__ u16 Bsf[2][128 * 32];
  const int tid  = threadIdx.x;
  const int lane = tid & 63, wave = tid >> 6;
  const int wr = wave >> 1, wc = wave & 1;
  const int col = lane & 15, grp = lane >> 4;
  const int m0 = blockIdx.y * 128, n0 = blockIdx.x * 128;

  const f32x4 fz = {0.f, 0.f, 0.f, 0.f};
  f32x4 acc[4][4];
#pragma unroll
  for (int i = 0; i < 4; i++)
#pragma unroll
    for (int j = 0; j < 4; j++) acc[i][j] = fz;

  const int arow = tid >> 2, akoff = (tid & 3) * 8;
  const u16* ag = A  + (size_t)(m0 + arow) * 768 + akoff;
  const u16* bg = Bt + (size_t)(n0 + arow) * 768 + akoff;
  const int lofs = wave * 512;

  gld_lds16(ag,                    &Asf[0][lofs]);
  gld_lds16(ag + (size_t)64 * 768, &Asf[0][lofs + 2048]);
  gld_lds16(bg,                    &Bsf[0][lofs]);
  gld_lds16(bg + (size_t)64 * 768, &Bsf[0][lofs + 2048]);

  int cur = 0;
  for (int kb = 0; kb < 768; kb += 32) {
    __syncthreads();
    if (kb + 32 < 768) {
      gld_lds16(ag + kb + 32,                    &Asf[cur ^ 1][lofs]);
      gld_lds16(ag + kb + 32 + (size_t)64 * 768, &Asf[cur ^ 1][lofs + 2048]);
      gld_lds16(bg + kb + 32,                    &Bsf[cur ^ 1][lofs]);
      gld_lds16(bg + kb + 32 + (size_t)64 * 768, &Bsf[cur ^ 1][lofs + 2048]);
    }

    bf16x8 af[4], bfr[4];
#pragma unroll
    for (int mt = 0; mt < 4; mt++) af[mt]  = *(const bf16x8*)&Asf[cur][(wr * 64 + mt * 16 + col) * 32 + grp * 8];
#pragma unroll
    for (int nt = 0; nt < 4; nt++) bfr[nt] = *(const bf16x8*)&Bsf[cur][(wc * 64 + nt * 16 + col) * 32 + grp * 8];
#pragma unroll
    for (int mt = 0; mt < 4; mt++)
#pragma unroll
      for (int nt = 0; nt < 4; nt++)
        acc[mt][nt] = __builtin_amdgcn_mfma_f32_16x16x32_bf16(af[mt], bfr[nt], acc[mt][nt], 0, 0, 0);
    cur ^= 1;
  }

#pragma unroll
  for (int mt = 0; mt < 4; mt++) {
#pragma unroll
    for (int r = 0; r < 4; r++) {
      const int mm = m0 + wr * 64 + mt * 16 + grp * 4 + r;
      if (mm >= MROWS) continue;
#pragma unroll
      for (int nt = 0; nt < 4; nt++) {
        const int c = n0 + wc * 64 + nt * 16 + col;
        out[(size_t)mm * 768 + c] = acc[mt][nt][r] + bias[c];
      }
    }
  }
}

// ---------------------------------------------------------------- attention v13
// v13 = v6 with KVBLK 64->128: stage 128 keys per dbuf tile, run the EXACT
// v6 per-64-key computation twice per barrier interval (nkv is always even:
// 34/32/26; text tail stays a singleton). Bitwise-identical math to v6 —
// only barrier placement changes. Barriers per block: 35 -> 18.
// Ks [2][128][72] (key-major), Vs [2][64][136] (d-major, key-axis widened).
__global__ __launch_bounds__(512) void attn_kernel(
    const u16* __restrict__ qkbuf, const u16* __restrict__ vt,
    const unsigned char* __restrict__ visu, const unsigned char* __restrict__ text,
    u16* __restrict__ attnout)
{
  __shared__ __align__(16) u16 Ks[2][128][72];
  __shared__ __align__(16) u16 Vs[2][64][136];
  __shared__ __align__(16) u64 mb64[34];
  __shared__ __align__(16) float lduf[8][32];

  const int tid  = threadIdx.x;
  const int lane = tid & 63, wave = tid >> 6;
  const int l31 = lane & 31, h = lane >> 5;

  // XCD swizzle: 864 blocks = 8 * 108; all tiles of one (b,h) on one XCD
  const int fid = blockIdx.x;
  const int swz = (fid & 7) * 108 + (fid >> 3);
  const int qtile = swz % 9;
  const int bh = swz / 9;
  const int b = bh / NH, hh = bh % NH;
  const int qt0 = qtile * 256;
  const int q0 = qt0 + wave * 32;
  const int qrow = q0 + l31;

  // ---- mask bitmask: one u64 per 64-key tile (keys >= 2121 masked) ----
  for (int c = wave; c < 34; c += 8) {
    const int key = c * 64 + lane;
    int mb = 1;
    if (key < 2101)      mb = visu[b * 2101 + key] ? 1 : 0;
    else if (key < 2121) mb = text[b * 20 + (key - 2101)] ? 1 : 0;
    const u64 bal = __ballot(mb != 0);
    if (lane == 0) mb64[c] = bal;
  }

  // Q B-fragments (pre-scaled by log2e/8 via wt scaling); clamp tail rows
  const int qload = (qrow < NSEQ) ? qrow : (NSEQ - 1);
  bf16x8 qf[4];
  {
    const u16* qp = qkbuf + (size_t)(b * NSEQ + qload) * 1536 + hh * 64 + h * 8;
#pragma unroll
    for (int s = 0; s < 4; s++) qf[s] = *(const bf16x8*)(qp + s * 16);
  }

  // per-lane key range (q = qrow)
  int ks, ke, ex;
  if (qrow == 0)        { ks = 0; ke = 2121; ex = 0; }
  else if (qrow < 1601) { ks = 1; ke = 1601; ex = 1; }
  else if (qrow < 2001) { ks = 1; ke = 2001; ex = 1; }
  else if (qrow < 2101) { ks = 1; ke = 2121; ex = 0; }
  else if (qrow < 2121) { ks = 0; ke = 2121; ex = 0; }
  else                  { ks = 0; ke = 0;    ex = 0; }

  // per-tile kv extent + optional text-tail block
  const int hi = (qt0 + 255 < 2120) ? (qt0 + 255) : 2120;
  int ke_tile, extra;
  if (qt0 == 0 || hi >= 2001) { ke_tile = 2121; extra = 0; }
  else if (hi >= 1601)        { ke_tile = 2001; extra = 1; }
  else                        { ke_tile = 1601; extra = 1; }
  const int nkv = (ke_tile + 63) >> 6;   // always even: 34 / 32 / 26
  const int npair = nkv >> 1;
  const int ntotp = npair + extra;

  f32x16 O0, O1;
#pragma unroll
  for (int i = 0; i < 16; i++) { O0[i] = 0.f; O1[i] = 0.f; }
  float lrun = 0.f;

  // K staging: thread -> (row = tid>>2 of 128 keys, dcols (tid&3)*16, two u16x8)
  // V staging: thread -> (d-row = tid>>3 of 64, keycols (tid&7)*16, two u16x8)
  const int srow = tid >> 2, skoff = (tid & 3) * 16;
  const int vd = tid >> 3, vkoff = (tid & 7) * 16;
  const size_t vbase = (size_t)(b * NH + hh) * 64 * NPAD;
  const u16* kbase = qkbuf + (size_t)(b * NSEQ + srow) * 1536 + 768 + hh * 64 + skoff;
  const u16* vsrc  = vt + vbase + (size_t)vd * NPAD + vkoff;

  // prologue: stage pair 0 into buf 0 (keys 0..127)
  {
    *(u16x8*)&Ks[0][srow][skoff]     = *(const u16x8*)kbase;
    *(u16x8*)&Ks[0][srow][skoff + 8] = *(const u16x8*)(kbase + 8);
    *(u16x8*)&Vs[0][vd][vkoff]       = *(const u16x8*)vsrc;
    *(u16x8*)&Vs[0][vd][vkoff + 8]   = *(const u16x8*)(vsrc + 8);
  }
  __syncthreads();

  u16x8 kpreA = {0,0,0,0,0,0,0,0}, kpreB = kpreA, vpreA = kpreA, vpreB = kpreA;

  for (int it = 0; it < ntotp; ++it) {
    const int cur = it & 1;
    const bool isPair = it < npair;
    const int kvbase = isPair ? it * 128 : 2096;
    const bool more = (it + 1 < ntotp);
    const bool nextPair = (it + 1 < npair);

    // (1) issue next tile's global loads into regs
    if (more) {
      const int nb = nextPair ? (it + 1) * 128 : 2096;
      if (nextPair || srow < 64) {
        const u16* kp = kbase + (size_t)nb * 1536;
        kpreA = *(const u16x8*)kp;
        kpreB = *(const u16x8*)(kp + 8);
      }
      if (nextPair || vkoff < 64) {
        const u16* vp = vsrc + nb;
        vpreA = *(const u16x8*)vp;
        vpreB = *(const u16x8*)(vp + 8);
      }
    }

    // (2) compute sub-tiles of 64 keys (exact v6 body per sub-tile)
    const int nsub = isPair ? 2 : 1;
    for (int sub = 0; sub < nsub; ++sub) {
      const int kv0 = kvbase + sub * 64;
      const int soff = sub * 64;

      const int skipl = (kv0 >= ke) && !((ex != 0) && (kv0 < 2121) && (kv0 + 64 > 2101));
      if (__all(skipl)) continue;

      f32x16 S0, S1;
#pragma unroll
      for (int i = 0; i < 16; i++) { S0[i] = 0.f; S1[i] = 0.f; }
      __builtin_amdgcn_s_setprio(1);
#pragma unroll
      for (int s = 0; s < 4; s++) {
        const bf16x8 k0 = *(const bf16x8*)&Ks[cur][soff + l31][s * 16 + h * 8];
        const bf16x8 k1 = *(const bf16x8*)&Ks[cur][soff + 32 + l31][s * 16 + h * 8];
        S0 = __builtin_amdgcn_mfma_f32_32x32x16_bf16(k0, qf[s], S0, 0, 0, 0);
        S1 = __builtin_amdgcn_mfma_f32_32x32x16_bf16(k1, qf[s], S1, 0, 0, 0);
      }
      __builtin_amdgcn_s_setprio(0);

      // masking: range + mask bit -> INVALID_S (exp2 -> exactly 0)
      const int fastl = (kv0 >= ks) && (kv0 + 64 <= ke);
      const u64 mword = isPair ? mb64[it * 2 + sub] : ((mb64[32] >> 48) | (mb64[33] << 16));
      const bool plain = __all(fastl) && (mword == 0ull);
      if (!plain) {
        const u32 wlo = (u32)mword, whi = (u32)(mword >> 32);
#pragma unroll
        for (int m = 0; m < 4; m++) {
#pragma unroll
          for (int r = 0; r < 4; r++) {
            const int bitpos = 8 * m + 4 * h + r;
            {
              const int key = kv0 + bitpos;
              bool valid = ((key >= ks) && (key < ke)) || ((ex != 0) && (key >= 2101));
              valid = valid && (((wlo >> bitpos) & 1u) == 0u);
              S0[4 * m + r] = valid ? S0[4 * m + r] : INVALID_S;
            }
            {
              const int key = kv0 + 32 + bitpos;
              bool valid = ((key >= ks) && (key < ke)) || ((ex != 0) && (key >= 2101));
              valid = valid && (((whi >> bitpos) & 1u) == 0u);
              S1[4 * m + r] = valid ? S1[4 * m + r] : INVALID_S;
            }
          }
        }
      }

      // static-max softmax: P = exp2(S)
      float ls = 0.f;
#pragma unroll
      for (int i = 0; i < 16; i++) { const float p = EXP2F(S0[i]); S0[i] = p; ls += p; }
#pragma unroll
      for (int i = 0; i < 16; i++) { const float p = EXP2F(S1[i]); S1[i] = p; ls += p; }
      lrun += ls;

      // P -> PV A-fragments (cvt_pk + permlane32_swap)
      bf16x8 pa[4];
      {
        u32 w[8];
#pragma unroll
        for (int j = 0; j < 8; j++) {
          u32 t;
          asm("v_cvt_pk_bf16_f32 %0, %1, %2" : "=v"(t) : "v"(S0[2 * j]), "v"(S0[2 * j + 1]));
          w[j] = t;
        }
        asm("v_permlane32_swap_b32 %0, %1" : "+v"(w[0]), "+v"(w[2]));
        asm("v_permlane32_swap_b32 %0, %1" : "+v"(w[1]), "+v"(w[3]));
        asm("v_permlane32_swap_b32 %0, %1" : "+v"(w[4]), "+v"(w[6]));
        asm("v_permlane32_swap_b32 %0, %1" : "+v"(w[5]), "+v"(w[7]));
        union { u32 u[4]; bf16x8 v; } f0, f1;
        f0.u[0] = w[0]; f0.u[1] = w[1]; f0.u[2] = w[2]; f0.u[3] = w[3];
        f1.u[0] = w[4]; f1.u[1] = w[5]; f1.u[2] = w[6]; f1.u[3] = w[7];
        pa[0] = f0.v; pa[1] = f1.v;
      }
      {
        u32 w[8];
#pragma unroll
        for (int j = 0; j < 8; j++) {
          u32 t;
          asm("v_cvt_pk_bf16_f32 %0, %1, %2" : "=v"(t) : "v"(S1[2 * j]), "v"(S1[2 * j + 1]));
          w[j] = t;
        }
        asm("v_permlane32_swap_b32 %0, %1" : "+v"(w[0]), "+v"(w[2]));
        asm("v_permlane32_swap_b32 %0, %1" : "+v"(w[1]), "+v"(w[3]));
        asm("v_permlane32_swap_b32 %0, %1" : "+v"(w[4]), "+v"(w[6]));
        asm("v_permlane32_swap_b32 %0, %1" : "+v"(w[5]), "+v"(w[7]));
        union { u32 u[4]; bf16x8 v; } f0, f1;
        f0.u[0] = w[0]; f0.u[1] = w[1]; f0.u[2] = w[2]; f0.u[3] = w[3];
        f1.u[0] = w[4]; f1.u[1] = w[5]; f1.u[2] = w[6]; f1.u[3] = w[7];
        pa[2] = f0.v; pa[3] = f1.v;
      }

      // PV: O[q][d] += P[q][k] * Vt[d][k]
      __builtin_amdgcn_s_setprio(1);
#pragma unroll
      for (int ck = 0; ck < 4; ck++) {
        const bf16x8 vf0 = *(const bf16x8*)&Vs[cur][l31][soff + ck * 16 + h * 8];
        const bf16x8 vf1 = *(const bf16x8*)&Vs[cur][32 + l31][soff + ck * 16 + h * 8];
        O0 = __builtin_amdgcn_mfma_f32_32x32x16_bf16(pa[ck], vf0, O0, 0, 0, 0);
        O1 = __builtin_amdgcn_mfma_f32_32x32x16_bf16(pa[ck], vf1, O1, 0, 0, 0);
      }
      __builtin_amdgcn_s_setprio(0);
    }

    // (3) stage next tile into buf[cur^1]
    if (more) {
      if (nextPair || srow < 64) {
        *(u16x8*)&Ks[cur ^ 1][srow][skoff]     = kpreA;
        *(u16x8*)&Ks[cur ^ 1][srow][skoff + 8] = kpreB;
      }
      if (nextPair || vkoff < 64) {
        *(u16x8*)&Vs[cur ^ 1][vd][vkoff]       = vpreA;
        *(u16x8*)&Vs[cur ^ 1][vd][vkoff + 8]   = vpreB;
      }
    }
    __syncthreads();
  }

  // epilogue: combine lane halves of l, normalize + store
  float ltot = lrun + __shfl_xor(lrun, 32);
  if (h == 0) lduf[wave][l31] = ltot;
#pragma unroll
  for (int m = 0; m < 4; m++) {
    const f32x4 lv = *(const f32x4*)&lduf[wave][8 * m + 4 * h];
#pragma unroll
    for (int r = 0; r < 4; r++) {
      const float linv = (lv[r] > 0.f) ? 1.0f / lv[r] : 0.f;
      const int n = q0 + 8 * m + 4 * h + r;
      if (n >= NSEQ) continue;
      u16* op = attnout + (size_t)(b * NSEQ + n) * 768 + hh * 64 + l31;
      op[0]  = f2bf(O0[4 * m + r] * linv);
      op[32] = f2bf(O1[4 * m + r] * linv);
    }
  }
}

// ----------------------------------------------------------------
extern "C" void kernel_launch(void* const* d_in, const int* in_sizes, int n_in,
                              void* d_out, int out_size, void* d_ws, size_t ws_size,
                              hipStream_t stream) {
  const float* src  = (const float*)d_in[0];
  const unsigned char* visu = (const unsigned char*)d_in[1];
  const unsigned char* text = (const unsigned char*)d_in[2];
  const float* w_qkv = (const float*)d_in[3];
  const float* w_proj = (const float*)d_in[4];
  const float* b_proj = (const float*)d_in[5];
  float* out = (float*)d_out;

  char* ws = (char*)d_ws;
  size_t off = 0;
  auto alloc = [&](size_t bytes) { char* p = ws + off; off += (bytes + 255) & ~(size_t)255; return p; };
  u16* wqkv_t  = (u16*)alloc((size_t)2304 * 768 * 2);
  u16* wproj_t = (u16*)alloc((size_t)768 * 768 * 2);
  u16* qk      = (u16*)alloc((size_t)MPAD * 1536 * 2);
  u16* vtb     = (u16*)alloc((size_t)NB * NH * 64 * NPAD * 2);
  u16* tmp0    = (u16*)alloc((size_t)MPAD * 768 * 2);   // srcb (pre-attn) then attnb
  (void)ws_size; (void)in_sizes; (void)n_in; (void)out_size;

  // Q pre-scale: (1/8) * log2(e)  -> softmax computed in base 2
  transpose_cast<<<dim3(2304 / 32, 768 / 32), dim3(32, 8), 0, stream>>>(w_qkv, wqkv_t, 768, 2304, 768, 0.125f * 1.4426950408889634f);
  transpose_cast<<<dim3(768 / 32, 768 / 32), dim3(32, 8), 0, stream>>>(w_proj, wproj_t, 768, 768, 0, 1.0f);
  cast_src_bf16<<<dim3(6363), dim3(256), 0, stream>>>(src, tmp0);   // 6363*256*8 == MROWS*768
  gemm_qkv_kernel<<<dim3(18, 133), dim3(256), 0, stream>>>(tmp0, wqkv_t, qk, vtb);
  attn_kernel<<<dim3(864), dim3(512), 0, stream>>>(qk, vtb, visu, text, tmp0);
  gemm_proj_kernel<<<dim3(6, 133), dim3(256), 0, stream>>>(tmp0, wproj_t, b_proj, out);
}